// Round 4
// baseline (723.599 us; speedup 1.0000x reference)
//
#include <hip/hip_runtime.h>

// Problem constants (setup_inputs): B=8, C=256, H=128, W=96, stride=1
constexpr int B_ = 8, C_ = 256, H_ = 128, W_ = 96;
constexpr int HW_ = H_ * W_;

typedef __bf16 bf16x8 __attribute__((ext_vector_type(8)));
typedef float f32x4 __attribute__((ext_vector_type(4)));

__device__ __forceinline__ float lrelu_f(float v) { return v > 0.f ? v : 0.1f * v; }
__device__ __forceinline__ ushort f2b(float v) {
    __bf16 h = (__bf16)v;
    return __builtin_bit_cast(ushort, h);
}
__device__ __forceinline__ float blo(unsigned u) {  // low ushort of packed pair -> f32
    return __builtin_bit_cast(float, u << 16);
}
__device__ __forceinline__ float bhi(unsigned u) {  // high ushort -> f32
    return __builtin_bit_cast(float, u & 0xffff0000u);
}

// Direct global->LDS async copy, 4 B per lane. LDS dest must be linear in
// lane order (wave-uniform base + lane*4) -- our staging maps are exactly
// e = k*768+tid linear, so this applies without layout change.
typedef __attribute__((address_space(1))) void gas_void;
typedef __attribute__((address_space(3))) void las_void;
__device__ __forceinline__ void gl_lds4(const float* g, float* l) {
    __builtin_amdgcn_global_load_lds((gas_void*)g, (las_void*)l, 4, 0, 0);
}

// ---------------------------------------------------------------------------
// Correlation + lrelu -> NHWC-64 bf16 (ch 0..48 data, 49..63 zero pad).
// v5 = v0 compute (same FP32 order -> bit-identical) with:
//  (a) double-buffered LDS + global_load_lds: next chunk's 20 loads issued
//      BEFORE compute, drained by the __syncthreads after compute. No data
//      ever held in registers -> no spill path (R1/R2 lesson).
//      Invalid halo lanes redirect their load address to a zeroed scratch.
//  (b) XOR bank swizzle, pre-swizzled-source form (LDS stays linear, rule
//      "both-sides-or-neither"): slot colp holds logical col colp^sw,
//      reads address (x0+4j)^sw.  sw2=(r&7)<<2 for s2, sw1=(ty&3)<<2 for s1.
//      Kills the same-bank collisions across r / ty at stride 128 / 96.
// ---------------------------------------------------------------------------
constexpr int CR = 4;
constexpr int F2R = 12;
constexpr int CCH = 8;

__global__ __launch_bounds__(768)
void corr_kernel(const float* __restrict__ f1, const float* __restrict__ f2,
                 const float* __restrict__ zero_src,
                 ushort* __restrict__ corr_nhwc)
{
    __shared__ __align__(16) float s2a[F2R * CCH * 128];   // 49152 B
    __shared__ __align__(16) float s2b[F2R * CCH * 128];   // 49152 B
    __shared__ __align__(16) float s1a[CCH * CR * 96];     // 12288 B
    __shared__ __align__(16) float s1b[CCH * CR * 96];     // 12288 B

    const int tid = threadIdx.x;
    const int pxg = tid % 24;
    const int ty = (tid / 24) % CR;
    const int dy = tid / 96;           // 0..7 (7 = pad-writer group)
    const int x0 = pxg * 4;

    const int b = blockIdx.x >> 5;
    const int y0 = (blockIdx.x & 31) * CR;

    float acc[7][4];
#pragma unroll
    for (int j = 0; j < 7; j++)
#pragma unroll
        for (int k = 0; k < 4; k++) acc[j][k] = 0.f;

    const float* f1p = f1 + b * C_ * HW_;
    const float* f2p = f2 + b * C_ * HW_;

    // Issue 20 direct-to-LDS loads for chunk cc into (s2d, s1d).
    // Addresses recomputed per call (NOT held across barriers -> no spill).
    auto STAGE = [&](int cc, float* s2d, float* s1d) {
#pragma unroll
        for (int k = 0; k < 16; k++) {
            int e = k * 768 + tid;
            int colp = e & 127;                    // physical LDS col
            int c = (e >> 7) & 7;
            int r = e >> 10;
            int coll = colp ^ ((r & 7) << 2);      // logical col (XOR swizzle)
            int yg = y0 + r - 3;
            int xg = coll - 3;
            bool valid = ((unsigned)yg < (unsigned)H_) && ((unsigned)xg < (unsigned)W_);
            int ygc = min(max(yg, 0), H_ - 1);
            int xgc = min(max(xg, 0), W_ - 1);
            const float* src = valid ? (f2p + (cc + c) * HW_ + ygc * W_ + xgc)
                                     : zero_src;
            gl_lds4(src, s2d + e);
        }
#pragma unroll
        for (int k = 0; k < 4; k++) {
            int e = k * 768 + tid;
            int idx = e / 96;
            int colp = e - idx * 96;
            int c = idx >> 2;
            int r = idx & 3;
            int coll = colp ^ ((r & 3) << 2);
            gl_lds4(f1p + (cc + c) * HW_ + (y0 + r) * W_ + coll, s1d + e);
        }
    };

    auto COMPUTE = [&](const float* s2c, const float* s1c) {
        const int r = ty + dy;
        const int sw2 = (r & 7) << 2;
        const int sw1 = (ty & 3) << 2;
#pragma unroll
        for (int c = 0; c < CCH; c++) {
            float4 v1 = *(const float4*)&s1c[(c * CR + ty) * 96 + (x0 ^ sw1)];
            float v1a[4] = {v1.x, v1.y, v1.z, v1.w};
            const float* rp = &s2c[(r * CCH + c) * 128];
            float4 a0 = *(const float4*)&rp[x0 ^ sw2];
            float4 a1 = *(const float4*)&rp[(x0 + 4) ^ sw2];
            float4 a2 = *(const float4*)&rp[(x0 + 8) ^ sw2];
            float iv[12] = {a0.x, a0.y, a0.z, a0.w, a1.x, a1.y, a1.z, a1.w,
                            a2.x, a2.y, a2.z, a2.w};
#pragma unroll
            for (int dx = 0; dx < 7; dx++)
#pragma unroll
                for (int p = 0; p < 4; p++)
                    acc[dx][p] += v1a[p] * iv[p + dx];
        }
    };

    STAGE(0, s2a, s1a);
    __syncthreads();                    // chunk 0 landed (vmcnt drained)

#pragma unroll 1
    for (int cc = 0; cc < C_; cc += 2 * CCH) {
        STAGE(cc + CCH, s2b, s1b);      // cc+8 < 256 always (cc <= 240)
        COMPUTE(s2a, s1a);
        __syncthreads();                // drains B's loads; A reads done
        if (cc + 2 * CCH < C_) STAGE(cc + 2 * CCH, s2a, s1a);
        COMPUTE(s2b, s1b);
        __syncthreads();
    }

    // Epilogue: transpose to NHWC-64 bf16 in LDS, then coalesced store.
    ushort* t = (ushort*)s2a;                   // [4][96][64] ushort = 49152 B
    const float scale = 1.f / 256.f;
    if (dy < 7) {
#pragma unroll
        for (int dx = 0; dx < 7; dx++)
#pragma unroll
            for (int p = 0; p < 4; p++)
                t[(ty * 96 + x0 + p) * 64 + dy * 7 + dx] =
                    f2b(lrelu_f(acc[dx][p] * scale));
    } else {
#pragma unroll
        for (int p = 0; p < 4; p++)
            for (int c = 49; c < 64; c++)
                t[(ty * 96 + x0 + p) * 64 + c] = 0;
    }
    __syncthreads();
    const uint4* src = (const uint4*)t;
    uint4* dst = (uint4*)(corr_nhwc + (size_t)(b * HW_ + y0 * W_) * 64);
    for (int e = tid; e < 3072; e += 768) dst[e] = src[e];
}

// ---------------------------------------------------------------------------
// Weight pack: [oc][ci][3][3] f32 -> [tap][oc][CIP] bf16 (ci >= CIN zeroed)
// ---------------------------------------------------------------------------
template <int CIN, int COUT, int CIP>
__global__ __launch_bounds__(256)
void pack_w(const float* __restrict__ w, ushort* __restrict__ wpk)
{
    int i = blockIdx.x * 256 + threadIdx.x;
    if (i >= 9 * COUT * CIP) return;
    int ci = i % CIP;
    int t = i / CIP;
    int oc = t % COUT;
    int tap = t / COUT;
    float v = (ci < CIN) ? w[(oc * CIN + ci) * 9 + tap] : 0.f;
    wpk[i] = f2b(v);
}

// ---------------------------------------------------------------------------
// MFMA shift-GEMM 3x3 conv (+bias+lrelu), NHWC bf16 in/out.
// ---------------------------------------------------------------------------
template <int CIP, int COUT, int OCB, int XT, int XTILES>
__global__ __launch_bounds__(256)
void conv_mfma(const ushort* __restrict__ in, const ushort* __restrict__ wpk,
               const float* __restrict__ bias, ushort* __restrict__ out)
{
    constexpr int OCF = OCB / 16, PXF = XT / 16, COLS = XT + 2;
    constexpr int G = CIP / 8, KC = CIP / 32;
    __shared__ __align__(16) ushort sIn[6 * COLS * CIP];

    const int tid = threadIdx.x;
    const int lane = tid & 63;
    const int ty = tid >> 6;          // wave id == row within tile
    const int ln = lane & 15;
    const int lq = lane >> 4;

    const int gx = blockIdx.x;
    const int xt = gx % XTILES;
    const int yt = (gx / XTILES) % 32;
    const int b = gx / (XTILES * 32);
    const int oc0 = blockIdx.y * OCB;
    const int x0 = xt * XT;
    const int y0 = yt * 4;

    // ---- stage input tile: rows y0-1..y0+4, cols x0-1..x0+XT ----
    constexpr int NU = 6 * COLS * G;   // 16B units
    for (int e = tid; e < NU; e += 256) {
        int g = e & (G - 1);
        int pc = e / G;
        int col = pc % COLS;
        int rr = pc / COLS;
        int yg = y0 - 1 + rr;
        int xg = x0 - 1 + col;
        uint4 v = make_uint4(0, 0, 0, 0);
        if ((unsigned)yg < (unsigned)H_ && (unsigned)xg < (unsigned)W_)
            v = *(const uint4*)(in + ((size_t)(b * HW_ + yg * W_ + xg) * CIP + g * 8));
        int p = rr * COLS + col;
        *(uint4*)(sIn + (size_t)(p * G + (g ^ (p & 7))) * 8) = v;
    }
    __syncthreads();

    f32x4 acc[OCF][PXF];
#pragma unroll
    for (int of = 0; of < OCF; of++)
#pragma unroll
        for (int pf = 0; pf < PXF; pf++) {
            f32x4 z = {0.f, 0.f, 0.f, 0.f};
            acc[of][pf] = z;
        }

    const uint4* wq = (const uint4*)wpk;
    for (int kc = 0; kc < KC; kc++) {
        for (int tap = 0; tap < 9; tap++) {
            const int r = tap / 3, s = tap % 3;
            bf16x8 afr[OCF];
#pragma unroll
            for (int of = 0; of < OCF; of++) {
                int off = ((tap * COUT + oc0 + of * 16 + ln) * CIP + kc * 32 + lq * 8) >> 3;
                afr[of] = __builtin_bit_cast(bf16x8, wq[off]);
            }
#pragma unroll
            for (int pf = 0; pf < PXF; pf++) {
                int p = (ty + r) * COLS + (pf * 16 + ln + s);
                int g = kc * 4 + lq;
                uint4 bv = *(const uint4*)(sIn + (size_t)(p * G + (g ^ (p & 7))) * 8);
                bf16x8 bfr = __builtin_bit_cast(bf16x8, bv);
#pragma unroll
                for (int of = 0; of < OCF; of++)
                    acc[of][pf] = __builtin_amdgcn_mfma_f32_16x16x32_bf16(
                        afr[of], bfr, acc[of][pf], 0, 0, 0);
            }
        }
    }

    // ---- epilogue: D col = lane&15 (px), row = lq*4+reg (oc) ----
    const int y = y0 + ty;
#pragma unroll
    for (int of = 0; of < OCF; of++) {
        int ocb = oc0 + of * 16 + lq * 4;
        float4 bv = *(const float4*)(bias + ocb);
        float bs[4] = {bv.x, bv.y, bv.z, bv.w};
#pragma unroll
        for (int pf = 0; pf < PXF; pf++) {
            int x = x0 + pf * 16 + ln;
            ushort4 pk;
            pk.x = f2b(lrelu_f(acc[of][pf][0] + bs[0]));
            pk.y = f2b(lrelu_f(acc[of][pf][1] + bs[1]));
            pk.z = f2b(lrelu_f(acc[of][pf][2] + bs[2]));
            pk.w = f2b(lrelu_f(acc[of][pf][3] + bs[3]));
            *(ushort4*)(out + ((size_t)(b * HW_ + y * W_ + x) * COUT + ocb)) = pk;
        }
    }
}

// ---------------------------------------------------------------------------
// conv4: NHWC-32 bf16 -> 2ch flow (f32, NCHW), no lrelu.
// ---------------------------------------------------------------------------
__global__ __launch_bounds__(256)
void conv4_kernel(const ushort* __restrict__ in, const float* __restrict__ wgt,
                  const float* __restrict__ bias, float* __restrict__ flow)
{
    __shared__ float s_w[2 * 9 * 32];   // [oc][tap][ci]
    const int tid = threadIdx.x;
    for (int e = tid; e < 576; e += 256) {
        int ci = e & 31;
        int t = e >> 5;
        int tap = t % 9;
        int oc = t / 9;
        s_w[e] = wgt[(oc * 32 + ci) * 9 + tap];
    }
    __syncthreads();

    int pix = blockIdx.x * 256 + tid;
    int b = pix / HW_;
    int rem = pix - b * HW_;
    int yy = rem / W_;
    int xx = rem - yy * W_;

    float a0 = bias[0], a1 = bias[1];
    for (int tap = 0; tap < 9; tap++) {
        int r = tap / 3, s = tap % 3;
        int yg = yy + r - 1, xg = xx + s - 1;
        if ((unsigned)yg >= (unsigned)H_ || (unsigned)xg >= (unsigned)W_) continue;
        const uint4* p = (const uint4*)(in + (size_t)(b * HW_ + yg * W_ + xg) * 32);
        const float* w0 = &s_w[(0 * 9 + tap) * 32];
        const float* w1 = &s_w[(1 * 9 + tap) * 32];
#pragma unroll
        for (int q = 0; q < 4; q++) {
            uint4 v = p[q];
            unsigned uu[4] = {v.x, v.y, v.z, v.w};
#pragma unroll
            for (int h = 0; h < 4; h++) {
                int ci = q * 8 + h * 2;
                float vl = blo(uu[h]), vh = bhi(uu[h]);
                a0 += vl * w0[ci] + vh * w0[ci + 1];
                a1 += vl * w1[ci] + vh * w1[ci + 1];
            }
        }
    }
    flow[(b * 2 + 0) * HW_ + rem] = a0;
    flow[(b * 2 + 1) * HW_ + rem] = a1;
}

// ---------------------------------------------------------------------------
// Warp: x_s = clamp(x+flow_x,0,W-1), y_s = clamp(y+flow_y,0,H-1); bilinear.
// Channel-split across blockIdx.y (4 x 64 ch) -> 1536 blocks for latency
// hiding on the gather loads. (Measured ~11 us better than unsplit, R1-R3.)
// ---------------------------------------------------------------------------
__global__ __launch_bounds__(256)
void warp_kernel(const float* __restrict__ f2, const float* __restrict__ flow,
                 float* __restrict__ out)
{
    int pix = blockIdx.x * 256 + threadIdx.x;
    int cbase = blockIdx.y * 64;
    int b = pix / HW_;
    int rem = pix - b * HW_;
    int yy = rem / W_;
    int xx = rem - yy * W_;

    float fx = flow[(b * 2 + 0) * HW_ + rem];
    float fy = flow[(b * 2 + 1) * HW_ + rem];
    float xs = fminf(fmaxf((float)xx + fx, 0.f), (float)(W_ - 1));
    float ys = fminf(fmaxf((float)yy + fy, 0.f), (float)(H_ - 1));
    float x0f = floorf(xs), y0f = floorf(ys);
    int x0 = (int)x0f, y0 = (int)y0f;
    float wx = xs - x0f, wy = ys - y0f;
    int x1 = min(x0 + 1, W_ - 1), y1 = min(y0 + 1, H_ - 1);

    int i00 = y0 * W_ + x0, i01 = y0 * W_ + x1;
    int i10 = y1 * W_ + x0, i11 = y1 * W_ + x1;
    float w00 = (1.f - wx) * (1.f - wy), w01 = wx * (1.f - wy);
    float w10 = (1.f - wx) * wy, w11 = wx * wy;

    const float* base = f2 + (size_t)(b * C_ + cbase) * HW_;
    float* ob = out + (size_t)(b * C_ + cbase) * HW_ + rem;
#pragma unroll 4
    for (int c = 0; c < 64; c++) {
        const float* p = base + c * HW_;
        ob[c * HW_] = p[i00] * w00 + p[i01] * w01 + p[i10] * w10 + p[i11] * w11;
    }
}

// ---------------------------------------------------------------------------
extern "C" void kernel_launch(void* const* d_in, const int* in_sizes, int n_in,
                              void* d_out, int out_size, void* d_ws, size_t ws_size,
                              hipStream_t stream)
{
    (void)in_sizes; (void)n_in; (void)out_size; (void)ws_size;
    const float* feat1 = (const float*)d_in[0];
    const float* feat2 = (const float*)d_in[1];
    const float* w1 = (const float*)d_in[2];
    const float* b1 = (const float*)d_in[3];
    const float* w2 = (const float*)d_in[4];
    const float* b2 = (const float*)d_in[5];
    const float* w3 = (const float*)d_in[6];
    const float* b3 = (const float*)d_in[7];
    const float* w4 = (const float*)d_in[8];
    const float* b4 = (const float*)d_in[9];

    // Workspace layout (bytes, all 256-aligned)
    char* ws = (char*)d_ws;
    ushort* corr_nhwc = (ushort*)(ws);                       // 98304*64*2  = 12,582,912
    ushort* h1 = (ushort*)(ws + 12582912);                   // 98304*128*2 = 25,165,824
    ushort* h2 = (ushort*)(ws + 37748736);                   // 98304*64*2  = 12,582,912
    ushort* h3 = (ushort*)(ws + 50331648);                   // 98304*32*2  =  6,291,456
    float* flow = (float*)(ws + 56623104);                   // 196608*4    =    786,432
    ushort* wpk1 = (ushort*)(ws + 57409536);                 // 73728*2     =    147,456
    ushort* wpk2 = (ushort*)(ws + 57556992);                 // 73728*2     =    147,456
    ushort* wpk3 = (ushort*)(ws + 57704448);                 // 18432*2     =     36,864
    float* out = (float*)d_out;

    // Zero scratch for corr's invalid-halo load redirect: first 256 B of the
    // h3 region (dead until conv3 writes it, long after corr completes).
    float* zero_src = (float*)(ws + 50331648);
    hipMemsetAsync(zero_src, 0, 256, stream);

    pack_w<49, 128, 64><<<288, 256, 0, stream>>>(w1, wpk1);
    pack_w<128, 64, 128><<<288, 256, 0, stream>>>(w2, wpk2);
    pack_w<64, 32, 64><<<72, 256, 0, stream>>>(w3, wpk3);

    corr_kernel<<<256, 768, 0, stream>>>(feat1, feat2, zero_src, corr_nhwc);
    // conv1: 49(->64) -> 128, tiles 48px, oc passes of 64
    conv_mfma<64, 128, 64, 48, 2><<<dim3(512, 2), 256, 0, stream>>>(corr_nhwc, wpk1, b1, h1);
    // conv2: 128 -> 64, tiles 32px
    conv_mfma<128, 64, 64, 32, 3><<<dim3(768, 1), 256, 0, stream>>>(h1, wpk2, b2, h2);
    // conv3: 64 -> 32, tiles 48px
    conv_mfma<64, 32, 32, 48, 2><<<dim3(512, 1), 256, 0, stream>>>(h2, wpk3, b3, h3);
    conv4_kernel<<<384, 256, 0, stream>>>(h3, w4, b4, flow);
    warp_kernel<<<dim3(384, 4), 256, 0, stream>>>(feat2, flow, out);
}

// Round 5
// 502.115 us; speedup vs baseline: 1.4411x; 1.4411x over previous
//
#include <hip/hip_runtime.h>

// Problem constants (setup_inputs): B=8, C=256, H=128, W=96, stride=1
constexpr int B_ = 8, C_ = 256, H_ = 128, W_ = 96;
constexpr int HW_ = H_ * W_;

typedef __bf16 bf16x8 __attribute__((ext_vector_type(8)));
typedef float f32x4 __attribute__((ext_vector_type(4)));

__device__ __forceinline__ float lrelu_f(float v) { return v > 0.f ? v : 0.1f * v; }
__device__ __forceinline__ ushort f2b(float v) {
    __bf16 h = (__bf16)v;
    return __builtin_bit_cast(ushort, h);
}
__device__ __forceinline__ float blo(unsigned u) {  // low ushort of packed pair -> f32
    return __builtin_bit_cast(float, u << 16);
}
__device__ __forceinline__ float bhi(unsigned u) {  // high ushort -> f32
    return __builtin_bit_cast(float, u & 0xffff0000u);
}

// ---------------------------------------------------------------------------
// Correlation, channel-split: block (h,t) accumulates channels h*128..h*128+127
// for tile t, writes f32 partial sums to P. Per-block code is EXACTLY the
// stable v0 structure (52 VGPR, no loop-carried prefetch state -- R1/R2/R4 all
// spilled; do not reintroduce pipelining here). Overlap comes from occupancy:
// grid 512 = 2 blocks/CU, so one block's stage phase hides under the other's
// compute. LDS staging is XOR-bank-swizzled on BOTH sides (plain ds_write
// staging, so swizzle is legal): store col^((r&7)<<2), read (x0+...)^sw.
// Breaks the stride-128/96 bank-phase tie behind the 1.54e7 conflicts.
// ---------------------------------------------------------------------------
constexpr int CR = 4;
constexpr int F2R = 12;
constexpr int CCH = 8;

__global__ __launch_bounds__(768)
void corr_split(const float* __restrict__ f1, const float* __restrict__ f2,
                float* __restrict__ P)
{
    __shared__ __align__(16) float s2[F2R * CCH * 128];   // 49152 B
    __shared__ __align__(16) float s1[CCH * CR * 96];     // 12288 B

    const int tid = threadIdx.x;
    const int pxg = tid % 24;
    const int ty = (tid / 24) % CR;
    const int dy = tid / 96;           // 0..7 (7 = pad group; acc unused)
    const int x0 = pxg * 4;

    const int bid = blockIdx.x;
    const int h = bid & 1;             // channel half
    const int t = bid >> 1;            // tile 0..255
    const int b = t >> 5;
    const int y0 = (t & 31) * CR;

    float acc[7][4];
#pragma unroll
    for (int j = 0; j < 7; j++)
#pragma unroll
        for (int k = 0; k < 4; k++) acc[j][k] = 0.f;

    const float* f1p = f1 + b * C_ * HW_;
    const float* f2p = f2 + b * C_ * HW_;

    // loop-invariant swizzled read offsets
    const int sw2 = ((ty + dy) & 7) << 2;
    const int xa = x0 ^ sw2, xb = (x0 + 4) ^ sw2, xc = (x0 + 8) ^ sw2;
    const int xd = x0 ^ (ty << 2);

    const int c0 = h * 128;
    for (int cc = c0; cc < c0 + 128; cc += CCH) {
        __syncthreads();
#pragma unroll
        for (int k = 0; k < 16; k++) {
            int e = k * 768 + tid;
            int col = e & 127;
            int c = (e >> 7) & 7;
            int r = e >> 10;
            int yg = y0 + r - 3;
            int xg = col - 3;
            bool valid = ((unsigned)yg < (unsigned)H_) && ((unsigned)xg < (unsigned)W_);
            int ygc = min(max(yg, 0), H_ - 1);
            int xgc = min(max(xg, 0), W_ - 1);
            float v = f2p[(cc + c) * HW_ + ygc * W_ + xgc];
            s2[(r * CCH + c) * 128 + (col ^ ((r & 7) << 2))] = valid ? v : 0.f;
        }
#pragma unroll
        for (int k = 0; k < 4; k++) {
            int e = k * 768 + tid;
            int idx = e / 96;
            int col = e - idx * 96;
            int c = idx >> 2;
            int r = idx & 3;
            s1[(c * CR + r) * 96 + (col ^ (r << 2))] =
                f1p[(cc + c) * HW_ + (y0 + r) * W_ + col];
        }
        __syncthreads();
#pragma unroll
        for (int c = 0; c < CCH; c++) {
            float4 v1 = *(const float4*)&s1[(c * CR + ty) * 96 + xd];
            float v1a[4] = {v1.x, v1.y, v1.z, v1.w};
            const float* rp = &s2[((ty + dy) * CCH + c) * 128];
            float4 a0 = *(const float4*)&rp[xa];
            float4 a1 = *(const float4*)&rp[xb];
            float4 a2 = *(const float4*)&rp[xc];
            float iv[12] = {a0.x, a0.y, a0.z, a0.w, a1.x, a1.y, a1.z, a1.w,
                            a2.x, a2.y, a2.z, a2.w};
#pragma unroll
            for (int dx = 0; dx < 7; dx++)
#pragma unroll
                for (int p = 0; p < 4; p++)
                    acc[dx][p] += v1a[p] * iv[p + dx];
        }
    }

    // Epilogue: fully-coalesced f32 partial writes, P[h][t][dy*7+dx][ty][96].
    if (dy < 7) {
        float* pb = P + ((size_t)(h * 256 + t) * 49 + dy * 7) * 384 + ty * 96 + x0;
#pragma unroll
        for (int dx = 0; dx < 7; dx++) {
            float4 v = {acc[dx][0], acc[dx][1], acc[dx][2], acc[dx][3]};
            *(float4*)(pb + dx * 384) = v;
        }
    }
}

// ---------------------------------------------------------------------------
// Reduce halves + scale + lrelu -> NHWC-64 bf16 (ch 49..63 zero), via the
// v0 LDS-transpose epilogue for coalesced 16B stores.
// ---------------------------------------------------------------------------
__global__ __launch_bounds__(768)
void corr_reduce(const float* __restrict__ P, ushort* __restrict__ corr_nhwc)
{
    __shared__ __align__(16) ushort t[4 * 96 * 64];   // 49152 B

    const int tid = threadIdx.x;
    const int pxg = tid % 24;
    const int ty = (tid / 24) % CR;
    const int dy = tid / 96;
    const int x0 = pxg * 4;
    const int ti = blockIdx.x;         // tile 0..255
    const int b = ti >> 5;
    const int y0 = (ti & 31) * CR;

    const float scale = 1.f / 256.f;
    if (dy < 7) {
        const float* p0 = P + ((size_t)(0 * 256 + ti) * 49 + dy * 7) * 384 + ty * 96 + x0;
        const float* p1 = P + ((size_t)(1 * 256 + ti) * 49 + dy * 7) * 384 + ty * 96 + x0;
#pragma unroll
        for (int dx = 0; dx < 7; dx++) {
            float4 a = *(const float4*)(p0 + dx * 384);
            float4 c = *(const float4*)(p1 + dx * 384);
            float s[4] = {a.x + c.x, a.y + c.y, a.z + c.z, a.w + c.w};
#pragma unroll
            for (int p = 0; p < 4; p++)
                t[(ty * 96 + x0 + p) * 64 + dy * 7 + dx] =
                    f2b(lrelu_f(s[p] * scale));
        }
    } else {
#pragma unroll
        for (int p = 0; p < 4; p++)
            for (int c = 49; c < 64; c++)
                t[(ty * 96 + x0 + p) * 64 + c] = 0;
    }
    __syncthreads();
    const uint4* src = (const uint4*)t;
    uint4* dst = (uint4*)(corr_nhwc + (size_t)(b * HW_ + y0 * W_) * 64);
    for (int e = tid; e < 3072; e += 768) dst[e] = src[e];
}

// ---------------------------------------------------------------------------
// Weight pack: [oc][ci][3][3] f32 -> [tap][oc][CIP] bf16 (ci >= CIN zeroed)
// ---------------------------------------------------------------------------
template <int CIN, int COUT, int CIP>
__global__ __launch_bounds__(256)
void pack_w(const float* __restrict__ w, ushort* __restrict__ wpk)
{
    int i = blockIdx.x * 256 + threadIdx.x;
    if (i >= 9 * COUT * CIP) return;
    int ci = i % CIP;
    int t = i / CIP;
    int oc = t % COUT;
    int tap = t / COUT;
    float v = (ci < CIN) ? w[(oc * CIN + ci) * 9 + tap] : 0.f;
    wpk[i] = f2b(v);
}

// ---------------------------------------------------------------------------
// MFMA shift-GEMM 3x3 conv (+bias+lrelu), NHWC bf16 in/out.
// ---------------------------------------------------------------------------
template <int CIP, int COUT, int OCB, int XT, int XTILES>
__global__ __launch_bounds__(256)
void conv_mfma(const ushort* __restrict__ in, const ushort* __restrict__ wpk,
               const float* __restrict__ bias, ushort* __restrict__ out)
{
    constexpr int OCF = OCB / 16, PXF = XT / 16, COLS = XT + 2;
    constexpr int G = CIP / 8, KC = CIP / 32;
    __shared__ __align__(16) ushort sIn[6 * COLS * CIP];

    const int tid = threadIdx.x;
    const int lane = tid & 63;
    const int ty = tid >> 6;          // wave id == row within tile
    const int ln = lane & 15;
    const int lq = lane >> 4;

    const int gx = blockIdx.x;
    const int xt = gx % XTILES;
    const int yt = (gx / XTILES) % 32;
    const int b = gx / (XTILES * 32);
    const int oc0 = blockIdx.y * OCB;
    const int x0 = xt * XT;
    const int y0 = yt * 4;

    // ---- stage input tile: rows y0-1..y0+4, cols x0-1..x0+XT ----
    constexpr int NU = 6 * COLS * G;   // 16B units
    for (int e = tid; e < NU; e += 256) {
        int g = e & (G - 1);
        int pc = e / G;
        int col = pc % COLS;
        int rr = pc / COLS;
        int yg = y0 - 1 + rr;
        int xg = x0 - 1 + col;
        uint4 v = make_uint4(0, 0, 0, 0);
        if ((unsigned)yg < (unsigned)H_ && (unsigned)xg < (unsigned)W_)
            v = *(const uint4*)(in + ((size_t)(b * HW_ + yg * W_ + xg) * CIP + g * 8));
        int p = rr * COLS + col;
        *(uint4*)(sIn + (size_t)(p * G + (g ^ (p & 7))) * 8) = v;
    }
    __syncthreads();

    f32x4 acc[OCF][PXF];
#pragma unroll
    for (int of = 0; of < OCF; of++)
#pragma unroll
        for (int pf = 0; pf < PXF; pf++) {
            f32x4 z = {0.f, 0.f, 0.f, 0.f};
            acc[of][pf] = z;
        }

    const uint4* wq = (const uint4*)wpk;
    for (int kc = 0; kc < KC; kc++) {
        for (int tap = 0; tap < 9; tap++) {
            const int r = tap / 3, s = tap % 3;
            bf16x8 afr[OCF];
#pragma unroll
            for (int of = 0; of < OCF; of++) {
                int off = ((tap * COUT + oc0 + of * 16 + ln) * CIP + kc * 32 + lq * 8) >> 3;
                afr[of] = __builtin_bit_cast(bf16x8, wq[off]);
            }
#pragma unroll
            for (int pf = 0; pf < PXF; pf++) {
                int p = (ty + r) * COLS + (pf * 16 + ln + s);
                int g = kc * 4 + lq;
                uint4 bv = *(const uint4*)(sIn + (size_t)(p * G + (g ^ (p & 7))) * 8);
                bf16x8 bfr = __builtin_bit_cast(bf16x8, bv);
#pragma unroll
                for (int of = 0; of < OCF; of++)
                    acc[of][pf] = __builtin_amdgcn_mfma_f32_16x16x32_bf16(
                        afr[of], bfr, acc[of][pf], 0, 0, 0);
            }
        }
    }

    // ---- epilogue: D col = lane&15 (px), row = lq*4+reg (oc) ----
    const int y = y0 + ty;
#pragma unroll
    for (int of = 0; of < OCF; of++) {
        int ocb = oc0 + of * 16 + lq * 4;
        float4 bv = *(const float4*)(bias + ocb);
        float bs[4] = {bv.x, bv.y, bv.z, bv.w};
#pragma unroll
        for (int pf = 0; pf < PXF; pf++) {
            int x = x0 + pf * 16 + ln;
            ushort4 pk;
            pk.x = f2b(lrelu_f(acc[of][pf][0] + bs[0]));
            pk.y = f2b(lrelu_f(acc[of][pf][1] + bs[1]));
            pk.z = f2b(lrelu_f(acc[of][pf][2] + bs[2]));
            pk.w = f2b(lrelu_f(acc[of][pf][3] + bs[3]));
            *(ushort4*)(out + ((size_t)(b * HW_ + y * W_ + x) * COUT + ocb)) = pk;
        }
    }
}

// ---------------------------------------------------------------------------
// conv4: NHWC-32 bf16 -> 2ch flow (f32, NCHW), no lrelu.
// ---------------------------------------------------------------------------
__global__ __launch_bounds__(256)
void conv4_kernel(const ushort* __restrict__ in, const float* __restrict__ wgt,
                  const float* __restrict__ bias, float* __restrict__ flow)
{
    __shared__ float s_w[2 * 9 * 32];   // [oc][tap][ci]
    const int tid = threadIdx.x;
    for (int e = tid; e < 576; e += 256) {
        int ci = e & 31;
        int t = e >> 5;
        int tap = t % 9;
        int oc = t / 9;
        s_w[e] = wgt[(oc * 32 + ci) * 9 + tap];
    }
    __syncthreads();

    int pix = blockIdx.x * 256 + tid;
    int b = pix / HW_;
    int rem = pix - b * HW_;
    int yy = rem / W_;
    int xx = rem - yy * W_;

    float a0 = bias[0], a1 = bias[1];
    for (int tap = 0; tap < 9; tap++) {
        int r = tap / 3, s = tap % 3;
        int yg = yy + r - 1, xg = xx + s - 1;
        if ((unsigned)yg >= (unsigned)H_ || (unsigned)xg >= (unsigned)W_) continue;
        const uint4* p = (const uint4*)(in + (size_t)(b * HW_ + yg * W_ + xg) * 32);
        const float* w0 = &s_w[(0 * 9 + tap) * 32];
        const float* w1 = &s_w[(1 * 9 + tap) * 32];
#pragma unroll
        for (int q = 0; q < 4; q++) {
            uint4 v = p[q];
            unsigned uu[4] = {v.x, v.y, v.z, v.w};
#pragma unroll
            for (int h = 0; h < 4; h++) {
                int ci = q * 8 + h * 2;
                float vl = blo(uu[h]), vh = bhi(uu[h]);
                a0 += vl * w0[ci] + vh * w0[ci + 1];
                a1 += vl * w1[ci] + vh * w1[ci + 1];
            }
        }
    }
    flow[(b * 2 + 0) * HW_ + rem] = a0;
    flow[(b * 2 + 1) * HW_ + rem] = a1;
}

// ---------------------------------------------------------------------------
// Warp: x_s = clamp(x+flow_x,0,W-1), y_s = clamp(y+flow_y,0,H-1); bilinear.
// Channel-split across blockIdx.y (4 x 64 ch) -> 1536 blocks for latency
// hiding on the gather loads. (Measured ~11 us better than unsplit, R1-R3.)
// ---------------------------------------------------------------------------
__global__ __launch_bounds__(256)
void warp_kernel(const float* __restrict__ f2, const float* __restrict__ flow,
                 float* __restrict__ out)
{
    int pix = blockIdx.x * 256 + threadIdx.x;
    int cbase = blockIdx.y * 64;
    int b = pix / HW_;
    int rem = pix - b * HW_;
    int yy = rem / W_;
    int xx = rem - yy * W_;

    float fx = flow[(b * 2 + 0) * HW_ + rem];
    float fy = flow[(b * 2 + 1) * HW_ + rem];
    float xs = fminf(fmaxf((float)xx + fx, 0.f), (float)(W_ - 1));
    float ys = fminf(fmaxf((float)yy + fy, 0.f), (float)(H_ - 1));
    float x0f = floorf(xs), y0f = floorf(ys);
    int x0 = (int)x0f, y0 = (int)y0f;
    float wx = xs - x0f, wy = ys - y0f;
    int x1 = min(x0 + 1, W_ - 1), y1 = min(y0 + 1, H_ - 1);

    int i00 = y0 * W_ + x0, i01 = y0 * W_ + x1;
    int i10 = y1 * W_ + x0, i11 = y1 * W_ + x1;
    float w00 = (1.f - wx) * (1.f - wy), w01 = wx * (1.f - wy);
    float w10 = (1.f - wx) * wy, w11 = wx * wy;

    const float* base = f2 + (size_t)(b * C_ + cbase) * HW_;
    float* ob = out + (size_t)(b * C_ + cbase) * HW_ + rem;
#pragma unroll 4
    for (int c = 0; c < 64; c++) {
        const float* p = base + c * HW_;
        ob[c * HW_] = p[i00] * w00 + p[i01] * w01 + p[i10] * w10 + p[i11] * w11;
    }
}

// ---------------------------------------------------------------------------
extern "C" void kernel_launch(void* const* d_in, const int* in_sizes, int n_in,
                              void* d_out, int out_size, void* d_ws, size_t ws_size,
                              hipStream_t stream)
{
    (void)in_sizes; (void)n_in; (void)out_size; (void)ws_size;
    const float* feat1 = (const float*)d_in[0];
    const float* feat2 = (const float*)d_in[1];
    const float* w1 = (const float*)d_in[2];
    const float* b1 = (const float*)d_in[3];
    const float* w2 = (const float*)d_in[4];
    const float* b2 = (const float*)d_in[5];
    const float* w3 = (const float*)d_in[6];
    const float* b3 = (const float*)d_in[7];
    const float* w4 = (const float*)d_in[8];
    const float* b4 = (const float*)d_in[9];

    // Workspace layout (bytes, all 256-aligned)
    char* ws = (char*)d_ws;
    ushort* corr_nhwc = (ushort*)(ws);                       // 98304*64*2  = 12,582,912
    ushort* h1 = (ushort*)(ws + 12582912);                   // 98304*128*2 = 25,165,824
    ushort* h2 = (ushort*)(ws + 37748736);                   // 98304*64*2  = 12,582,912
    ushort* h3 = (ushort*)(ws + 50331648);                   // 98304*32*2  =  6,291,456
    float* flow = (float*)(ws + 56623104);                   // 196608*4    =    786,432
    ushort* wpk1 = (ushort*)(ws + 57409536);                 // 73728*2     =    147,456
    ushort* wpk2 = (ushort*)(ws + 57556992);                 // 73728*2     =    147,456
    ushort* wpk3 = (ushort*)(ws + 57704448);                 // 18432*2     =     36,864
    float* out = (float*)d_out;

    // Corr partial sums: 2*256*49*384 f32 = 38,535,168 B. Lives in the
    // h1/h2/h3 region (offset 12,582,912..51,118,080), which is dead until
    // conv1 runs -- P is consumed by corr_reduce before that.
    float* Ppart = (float*)(ws + 12582912);

    pack_w<49, 128, 64><<<288, 256, 0, stream>>>(w1, wpk1);
    pack_w<128, 64, 128><<<288, 256, 0, stream>>>(w2, wpk2);
    pack_w<64, 32, 64><<<72, 256, 0, stream>>>(w3, wpk3);

    corr_split<<<512, 768, 0, stream>>>(feat1, feat2, Ppart);
    corr_reduce<<<256, 768, 0, stream>>>(Ppart, corr_nhwc);
    // conv1: 49(->64) -> 128, tiles 48px, oc passes of 64
    conv_mfma<64, 128, 64, 48, 2><<<dim3(512, 2), 256, 0, stream>>>(corr_nhwc, wpk1, b1, h1);
    // conv2: 128 -> 64, tiles 32px
    conv_mfma<128, 64, 64, 32, 3><<<dim3(768, 1), 256, 0, stream>>>(h1, wpk2, b2, h2);
    // conv3: 64 -> 32, tiles 48px
    conv_mfma<64, 32, 32, 48, 2><<<dim3(512, 1), 256, 0, stream>>>(h2, wpk3, b3, h3);
    conv4_kernel<<<384, 256, 0, stream>>>(h3, w4, b4, flow);
    warp_kernel<<<dim3(384, 4), 256, 0, stream>>>(feat2, flow, out);
}